// Round 5
// baseline (352.594 us; speedup 1.0000x reference)
//
#include <hip/hip_runtime.h>
#include <hip/hip_bf16.h>

#define N_NODES 50000
#define N_EDGES 500000
#define IN_CH 128
#define OUT_CH 128
#define N_TYPES 2
#define NEG_SLOPE 0.2f
#define EPS_F 1e-16f

// ---------------------------------------------------------------------------
// Kernel 0: transpose root_w [128][128] -> rwt (so gemm stages it like weight)
// ---------------------------------------------------------------------------
__global__ __launch_bounds__(256) void transpose_rootw_kernel(
    const float* __restrict__ rw, float* __restrict__ rwt)
{
    __shared__ float t[32][33];
    const int bx = blockIdx.x & 3;    // source col block
    const int by = blockIdx.x >> 2;   // source row block
    const int lx = threadIdx.x & 31;
    const int ly = threadIdx.x >> 5;  // 0..7
    #pragma unroll
    for (int i = 0; i < 4; ++i)
        t[ly + i * 8][lx] = rw[(size_t)(by * 32 + ly + i * 8) * 128 + bx * 32 + lx];
    __syncthreads();
    #pragma unroll
    for (int i = 0; i < 4; ++i)
        rwt[(size_t)(bx * 32 + ly + i * 8) * 128 + by * 32 + lx] = t[lx][ly + i * 8];
}

// ---------------------------------------------------------------------------
// Kernel 1: fused GEMM  C[50000,384] = X[50000,128] @ [W0|W1|rwt]
//   chunk 0/1 -> hall[n][t][o], chunk 2 -> out[n][o] + root_b
// BK=32 (33KB LDS -> 4 blocks/CU); inner loop 4-kk, all-b128 LDS reads.
// ---------------------------------------------------------------------------
#define TM 32
#define BK 32
#define BS_STRIDE 132

__global__ __launch_bounds__(256) void gemm_kernel(
    const float* __restrict__ x, const float* __restrict__ weight,
    const float* __restrict__ rwt, const float* __restrict__ root_b,
    float* __restrict__ hall, float* __restrict__ out)
{
    __shared__ float xs[TM][IN_CH];
    __shared__ float Bs[BK][BS_STRIDE];

    const int tid = threadIdx.x;
    const int block_n0 = blockIdx.x * TM;
    const int n0 = (tid >> 5) * 4;   // node group
    const int o0 = (tid & 31) * 4;   // output group

    // stage x tile: 32 nodes x 128 ch, coalesced float4
    {
        const float4* xg = (const float4*)x;
        #pragma unroll
        for (int i = 0; i < 4; ++i) {
            int idx = tid + i * 256;
            int n = idx >> 5;
            int c4 = idx & 31;
            int gn = block_n0 + n;
            float4 v = make_float4(0.f, 0.f, 0.f, 0.f);
            if (gn < N_NODES) v = xg[(size_t)gn * 32 + c4];
            *(float4*)&xs[n][c4 * 4] = v;
        }
    }

    for (int c = 0; c < 3; ++c) {
        const float* bsrc = (c < 2) ? (weight + (size_t)c * IN_CH * OUT_CH) : rwt;
        float acc[4][4] = {};
        #pragma unroll
        for (int kh = 0; kh < 4; ++kh) {
            __syncthreads();
            {
                const float4* wg = (const float4*)(bsrc + (size_t)kh * BK * OUT_CH);
                #pragma unroll
                for (int i = 0; i < 4; ++i) {
                    int idx = tid + i * 256;
                    int kk = idx >> 5;
                    int c4 = idx & 31;
                    *(float4*)&Bs[kk][c4 * 4] = wg[kk * 32 + c4];
                }
            }
            __syncthreads();

            #pragma unroll
            for (int kk = 0; kk < BK; kk += 4) {
                float4 bv0 = *(const float4*)&Bs[kk + 0][o0];
                float4 bv1 = *(const float4*)&Bs[kk + 1][o0];
                float4 bv2 = *(const float4*)&Bs[kk + 2][o0];
                float4 bv3 = *(const float4*)&Bs[kk + 3][o0];
                #pragma unroll
                for (int i = 0; i < 4; ++i) {
                    float4 xv = *(const float4*)&xs[n0 + i][kh * BK + kk];
                    acc[i][0] += xv.x * bv0.x + xv.y * bv1.x + xv.z * bv2.x + xv.w * bv3.x;
                    acc[i][1] += xv.x * bv0.y + xv.y * bv1.y + xv.z * bv2.y + xv.w * bv3.y;
                    acc[i][2] += xv.x * bv0.z + xv.y * bv1.z + xv.z * bv2.z + xv.w * bv3.z;
                    acc[i][3] += xv.x * bv0.w + xv.y * bv1.w + xv.z * bv2.w + xv.w * bv3.w;
                }
            }
        }

        if (c < 2) {
            #pragma unroll
            for (int i = 0; i < 4; ++i) {
                int gn = block_n0 + n0 + i;
                if (gn < N_NODES) {
                    float4 v = make_float4(acc[i][0], acc[i][1], acc[i][2], acc[i][3]);
                    *(float4*)&hall[((size_t)gn * 2 + c) * 128 + o0] = v;
                }
            }
        } else {
            float4 bias = *(const float4*)&root_b[o0];
            #pragma unroll
            for (int i = 0; i < 4; ++i) {
                int gn = block_n0 + n0 + i;
                if (gn < N_NODES) {
                    float4 v = make_float4(acc[i][0] + bias.x, acc[i][1] + bias.y,
                                           acc[i][2] + bias.z, acc[i][3] + bias.w);
                    *(float4*)&out[(size_t)gn * 128 + o0] = v;
                }
            }
        }
    }
}

// ---------------------------------------------------------------------------
// CSR build: histogram -> block scan -> block-sum scan -> add -> scatter ids
// ---------------------------------------------------------------------------
__global__ __launch_bounds__(256) void hist_kernel(
    const int* __restrict__ ei, int* __restrict__ deg)
{
    int i = blockIdx.x * 256 + threadIdx.x;
    if (i < N_EDGES) atomicAdd(&deg[ei[N_EDGES + i]], 1);
}

__global__ __launch_bounds__(256) void scan1_kernel(
    const int* __restrict__ deg, int* __restrict__ rp, int* __restrict__ bsum)
{
    __shared__ int s[256];
    int i = blockIdx.x * 256 + threadIdx.x;
    int v = (i < N_NODES) ? deg[i] : 0;
    s[threadIdx.x] = v;
    __syncthreads();
    #pragma unroll
    for (int off = 1; off < 256; off <<= 1) {
        int t = (threadIdx.x >= off) ? s[threadIdx.x - off] : 0;
        __syncthreads();
        s[threadIdx.x] += t;
        __syncthreads();
    }
    if (i < N_NODES) rp[i + 1] = s[threadIdx.x];
    if (threadIdx.x == 255) bsum[blockIdx.x] = s[255];
    if (i == 0) rp[0] = 0;
}

__global__ __launch_bounds__(256) void scan2_kernel(int* __restrict__ bsum, int nb)
{
    __shared__ int s[256];
    int tid = threadIdx.x;
    int v = (tid < nb) ? bsum[tid] : 0;
    s[tid] = v;
    __syncthreads();
    #pragma unroll
    for (int off = 1; off < 256; off <<= 1) {
        int t = (tid >= off) ? s[tid - off] : 0;
        __syncthreads();
        s[tid] += t;
        __syncthreads();
    }
    if (tid < nb) bsum[tid] = s[tid] - v;          // exclusive
}

__global__ __launch_bounds__(256) void scan3_kernel(
    int* __restrict__ rp, const int* __restrict__ bsum)
{
    int i = blockIdx.x * 256 + threadIdx.x;
    if (i < N_NODES) rp[i + 1] += bsum[blockIdx.x];
}

__global__ __launch_bounds__(256) void csr_scatter_kernel(
    const int* __restrict__ ei, const int* __restrict__ etype,
    const int* __restrict__ rp, int* __restrict__ cursor, int* __restrict__ skey)
{
    int i = blockIdx.x * 256 + threadIdx.x;
    if (i >= N_EDGES) return;
    int dst = ei[N_EDGES + i];
    int pos = rp[dst] + atomicAdd(&cursor[dst], 1);
    skey[pos] = (ei[i] << 1) | (etype[i] & 1);
}

// ---------------------------------------------------------------------------
// Fused per-node kernel: one wave per node, online softmax, 4-edge batches
// (4 gathers + 4 independent shuffle-reduce chains in flight per iteration).
// ---------------------------------------------------------------------------
__global__ __launch_bounds__(256) void node_agg_kernel(
    const int* __restrict__ rp, const int* __restrict__ skey,
    const float* __restrict__ hall, const float* __restrict__ att,
    float* __restrict__ out)
{
    const int lane = threadIdx.x & 63;
    const int node = (blockIdx.x * 256 + threadIdx.x) >> 6;
    if (node >= N_NODES) return;
    const int row0 = rp[node], row1 = rp[node + 1];
    if (row0 == row1) return;   // out keeps root contribution

    const float2 al0 = *(const float2*)&att[0 * 256 + lane * 2];
    const float2 ar0 = *(const float2*)&att[0 * 256 + 128 + lane * 2];
    const float2 al1 = *(const float2*)&att[1 * 256 + lane * 2];
    const float2 ar1 = *(const float2*)&att[1 * 256 + 128 + lane * 2];

    // per-node dst-side logit contribution, both types, wave-reduced
    const float2 hd0 = *(const float2*)&hall[((size_t)node * 2 + 0) * 128 + lane * 2];
    const float2 hd1 = *(const float2*)&hall[((size_t)node * 2 + 1) * 128 + lane * 2];
    float dr0 = hd0.x * ar0.x + hd0.y * ar0.y;
    float dr1 = hd1.x * ar1.x + hd1.y * ar1.y;
    #pragma unroll
    for (int off = 32; off; off >>= 1) {
        dr0 += __shfl_xor(dr0, off);
        dr1 += __shfl_xor(dr1, off);
    }

    const float NINF = -__builtin_inff();
    float m = NINF, denom = 0.f, a0 = 0.f, a1 = 0.f;

    for (int j = row0; j < row1; j += 4) {
        const int je = row1 - 1;
        const int k0 = skey[j];
        const int k1 = skey[min(j + 1, je)];
        const int k2 = skey[min(j + 2, je)];
        const int k3 = skey[min(j + 3, je)];
        const int t0 = k0 & 1, t1 = k1 & 1, t2 = k2 & 1, t3 = k3 & 1;

        const float2 h0 = *(const float2*)&hall[((size_t)(k0 >> 1) * 2 + t0) * 128 + lane * 2];
        const float2 h1 = *(const float2*)&hall[((size_t)(k1 >> 1) * 2 + t1) * 128 + lane * 2];
        const float2 h2 = *(const float2*)&hall[((size_t)(k2 >> 1) * 2 + t2) * 128 + lane * 2];
        const float2 h3 = *(const float2*)&hall[((size_t)(k3 >> 1) * 2 + t3) * 128 + lane * 2];

        const float2 A0 = t0 ? al1 : al0;
        const float2 A1 = t1 ? al1 : al0;
        const float2 A2 = t2 ? al1 : al0;
        const float2 A3 = t3 ? al1 : al0;

        float p0 = h0.x * A0.x + h0.y * A0.y;
        float p1 = h1.x * A1.x + h1.y * A1.y;
        float p2 = h2.x * A2.x + h2.y * A2.y;
        float p3 = h3.x * A3.x + h3.y * A3.y;
        #pragma unroll
        for (int off = 32; off; off >>= 1) {
            p0 += __shfl_xor(p0, off);
            p1 += __shfl_xor(p1, off);
            p2 += __shfl_xor(p2, off);
            p3 += __shfl_xor(p3, off);
        }

        float e0 = p0 + (t0 ? dr1 : dr0);
        float e1 = p1 + (t1 ? dr1 : dr0);
        float e2 = p2 + (t2 ? dr1 : dr0);
        float e3 = p3 + (t3 ? dr1 : dr0);
        e0 = (e0 > 0.f) ? e0 : NEG_SLOPE * e0;
        e1 = (e1 > 0.f) ? e1 : NEG_SLOPE * e1;
        e2 = (e2 > 0.f) ? e2 : NEG_SLOPE * e2;
        e3 = (e3 > 0.f) ? e3 : NEG_SLOPE * e3;
        // mask batch tail (wave-uniform): invalid -> -inf -> weight 0
        if (j + 1 > je) e1 = NINF;
        if (j + 2 > je) e2 = NINF;
        if (j + 3 > je) e3 = NINF;

        const float mx = fmaxf(fmaxf(fmaxf(e0, e1), fmaxf(e2, e3)), m);
        if (mx > m) {                        // wave-uniform
            const float r = __expf(m - mx);  // first batch: exp(-inf)=0
            denom *= r; a0 *= r; a1 *= r;
            m = mx;
        }
        const float w0 = __expf(e0 - m);
        const float w1 = __expf(e1 - m);
        const float w2 = __expf(e2 - m);
        const float w3 = __expf(e3 - m);
        denom += (w0 + w1) + (w2 + w3);
        a0 += w0 * h0.x + w1 * h1.x + w2 * h2.x + w3 * h3.x;
        a1 += w0 * h0.y + w1 * h1.y + w2 * h2.y + w3 * h3.y;
    }
    const float inv = 1.f / (denom + EPS_F);
    float* op = &out[(size_t)node * 128 + lane * 2];
    op[0] += a0 * inv;
    op[1] += a1 * inv;
}

// ---------------------------------------------------------------------------
extern "C" void kernel_launch(void* const* d_in, const int* in_sizes, int n_in,
                              void* d_out, int out_size, void* d_ws, size_t ws_size,
                              hipStream_t stream) {
    const float* x      = (const float*)d_in[0];
    const int*   ei     = (const int*)d_in[1];
    const int*   etype  = (const int*)d_in[2];
    const float* weight = (const float*)d_in[3];
    const float* att    = (const float*)d_in[4];
    const float* root_w = (const float*)d_in[5];
    const float* root_b = (const float*)d_in[6];
    float* out = (float*)d_out;

    // ws: hall [N*2*128] | deg [N] | cursor [N] | rp [N+1] | bsum [256] | skey [E] | rwt [128*128]
    float* hall  = (float*)d_ws;
    int* deg     = (int*)(hall + (size_t)N_NODES * 2 * 128);
    int* cursor  = deg + N_NODES;
    int* rp      = cursor + N_NODES;
    int* bsum    = rp + (N_NODES + 1);
    int* skey    = bsum + 256;
    float* rwt   = (float*)(skey + N_EDGES);

    const int NB_E = (N_EDGES + 255) / 256;
    const int NB_N = (N_NODES + 255) / 256;

    hipMemsetAsync(deg, 0, sizeof(int) * (size_t)N_NODES * 2, stream);

    transpose_rootw_kernel<<<16, 256, 0, stream>>>(root_w, rwt);

    gemm_kernel<<<(N_NODES + TM - 1) / TM, 256, 0, stream>>>(
        x, weight, rwt, root_b, hall, out);

    hist_kernel<<<NB_E, 256, 0, stream>>>(ei, deg);
    scan1_kernel<<<NB_N, 256, 0, stream>>>(deg, rp, bsum);
    scan2_kernel<<<1, 256, 0, stream>>>(bsum, NB_N);
    scan3_kernel<<<NB_N, 256, 0, stream>>>(rp, bsum);
    csr_scatter_kernel<<<NB_E, 256, 0, stream>>>(ei, etype, rp, cursor, skey);

    node_agg_kernel<<<(N_NODES + 3) / 4, 256, 0, stream>>>(
        rp, skey, hall, att, out);
}

// Round 8
// 249.774 us; speedup vs baseline: 1.4117x; 1.4117x over previous
//
#include <hip/hip_runtime.h>
#include <hip/hip_bf16.h>

#define N_NODES 50000
#define N_EDGES 500000
#define IN_CH 128
#define OUT_CH 128
#define N_TYPES 2
#define NEG_SLOPE 0.2f
#define EPS_F 1e-16f

typedef __attribute__((ext_vector_type(8))) short bf16x8;
typedef __attribute__((ext_vector_type(4))) float f32x4;

// fp32 -> bf16 (RNE) bit helpers
__device__ __forceinline__ unsigned short bf16_rne(float f) {
    unsigned int u = __float_as_uint(f);
    u += 0x7FFFu + ((u >> 16) & 1u);
    return (unsigned short)(u >> 16);
}
__device__ __forceinline__ float bf16_to_f32(unsigned short h) {
    return __uint_as_float(((unsigned int)h) << 16);
}

// ---------------------------------------------------------------------------
// Kernel 0: build Bt_hi/Bt_lo [384][128] bf16 (B transposed, split hi/lo)
//   rows 0..127  = W0^T  (Bt[o][k] = weight[0][k][o])
//   rows 128..255= W1^T
//   rows 256..383= root_w (already [o][k])
// ---------------------------------------------------------------------------
__global__ __launch_bounds__(256) void bprep_kernel(
    const float* __restrict__ weight, const float* __restrict__ root_w,
    unsigned short* __restrict__ bt_hi, unsigned short* __restrict__ bt_lo)
{
    int i = blockIdx.x * 256 + threadIdx.x;       // 0..49151
    if (i >= 384 * 128) return;
    int n = i >> 7, k = i & 127;
    float v;
    if (n < 256) {
        int t = n >> 7, o = n & 127;
        v = weight[(size_t)t * 16384 + (size_t)k * 128 + o];
    } else {
        v = root_w[(size_t)(n - 256) * 128 + k];
    }
    unsigned short h = bf16_rne(v);
    float lo = v - bf16_to_f32(h);
    bt_hi[i] = h;
    bt_lo[i] = bf16_rne(lo);
}

// ---------------------------------------------------------------------------
// Kernel 1: bf16x3 split-MFMA GEMM.  C[50048,384] = X[.,128] @ B[128,384]
//   grid = 3 chunks * 391 m-blocks (chunk-major -> B chunk L2-resident).
//   Per block: stage x fp32 -> A_hi/A_lo bf16 LDS (conversion fused),
//   stage Bt chunk, one barrier, 4 waves * 64x64, K=128 in 4 ksteps,
//   3 MFMA passes (hh, hl, lh).  XOR swizzle col^=(row&7)<<3 both sides.
// ---------------------------------------------------------------------------
#define MBLK 391
#define LSWZ(row, col) ((row) * 128 + ((col) ^ (((row) & 7) << 3)))

__global__ __launch_bounds__(256) void mfma_gemm_kernel(
    const float* __restrict__ x,
    const unsigned short* __restrict__ bt_hi,
    const unsigned short* __restrict__ bt_lo,
    const float* __restrict__ root_b,
    float* __restrict__ hall, float* __restrict__ out)
{
    __shared__ unsigned short Ah[128 * 128];
    __shared__ unsigned short Al[128 * 128];
    __shared__ unsigned short Bh[128 * 128];
    __shared__ unsigned short Bl[128 * 128];

    const int tid = threadIdx.x;
    const int bid = blockIdx.x;
    const int c = bid / MBLK;            // output chunk 0..2
    const int m0 = (bid - c * MBLK) * 128;

    // --- stage A: x fp32 -> hi/lo bf16 (4096 float4 loads, 16/thread)
    {
        const float4* xg = (const float4*)x;
        #pragma unroll
        for (int it = 0; it < 16; ++it) {
            int idx = tid + it * 256;        // 0..4095
            int r = idx >> 5, c4 = idx & 31; // row, float4-in-row
            int gn = m0 + r;
            float4 v = make_float4(0.f, 0.f, 0.f, 0.f);
            if (gn < N_NODES) v = xg[(size_t)gn * 32 + c4];
            unsigned short h0 = bf16_rne(v.x), h1 = bf16_rne(v.y),
                           h2 = bf16_rne(v.z), h3 = bf16_rne(v.w);
            ushort4 hh = make_ushort4(h0, h1, h2, h3);
            ushort4 ll = make_ushort4(bf16_rne(v.x - bf16_to_f32(h0)),
                                      bf16_rne(v.y - bf16_to_f32(h1)),
                                      bf16_rne(v.z - bf16_to_f32(h2)),
                                      bf16_rne(v.w - bf16_to_f32(h3)));
            int off = LSWZ(r, c4 * 4);
            *(ushort4*)&Ah[off] = hh;
            *(ushort4*)&Al[off] = ll;
        }
    }

    // --- stage B chunk rows c*128..c*128+127 (16B loads, 8/thread/matrix)
    {
        const float4* bhg = (const float4*)(bt_hi + (size_t)c * 128 * 128);
        const float4* blg = (const float4*)(bt_lo + (size_t)c * 128 * 128);
        #pragma unroll
        for (int it = 0; it < 8; ++it) {
            int f4 = tid + it * 256;         // 0..2047 (16B units)
            int r = f4 >> 4, c8 = f4 & 15;   // row, 8-elem group
            int off = LSWZ(r, c8 * 8);
            *(float4*)&Bh[off] = bhg[f4];
            *(float4*)&Bl[off] = blg[f4];
        }
    }
    __syncthreads();

    // --- compute: 4 waves, each 64x64 tile
    const int lane = tid & 63;
    const int w = tid >> 6;
    const int mh = (w >> 1) * 64;
    const int nh = (w & 1) * 64;
    const int lr = lane & 15;            // A row / B col within fragment
    const int lk = (lane >> 4) * 8;      // k offset within fragment

    f32x4 acc[4][4];
    #pragma unroll
    for (int mi = 0; mi < 4; ++mi)
        #pragma unroll
        for (int ni = 0; ni < 4; ++ni)
            acc[mi][ni] = (f32x4){0.f, 0.f, 0.f, 0.f};

    #pragma unroll
    for (int ks = 0; ks < 4; ++ks) {
        const int ko = ks * 32 + lk;
        bf16x8 ah[4], al[4], bh[4], bl[4];
        #pragma unroll
        for (int mi = 0; mi < 4; ++mi) {
            int off = LSWZ(mh + mi * 16 + lr, ko);
            ah[mi] = *(const bf16x8*)&Ah[off];
            al[mi] = *(const bf16x8*)&Al[off];
        }
        #pragma unroll
        for (int ni = 0; ni < 4; ++ni) {
            int off = LSWZ(nh + ni * 16 + lr, ko);
            bh[ni] = *(const bf16x8*)&Bh[off];
            bl[ni] = *(const bf16x8*)&Bl[off];
        }
        #pragma unroll
        for (int mi = 0; mi < 4; ++mi)
            #pragma unroll
            for (int ni = 0; ni < 4; ++ni) {
                acc[mi][ni] = __builtin_amdgcn_mfma_f32_16x16x32_bf16(
                    ah[mi], bh[ni], acc[mi][ni], 0, 0, 0);
                acc[mi][ni] = __builtin_amdgcn_mfma_f32_16x16x32_bf16(
                    ah[mi], bl[ni], acc[mi][ni], 0, 0, 0);
                acc[mi][ni] = __builtin_amdgcn_mfma_f32_16x16x32_bf16(
                    al[mi], bh[ni], acc[mi][ni], 0, 0, 0);
            }
    }

    // --- write C (verified layout: col = lane&15, row = (lane>>4)*4 + reg)
    const int crow = (lane >> 4) * 4;
    const int ccol = lane & 15;
    if (c < 2) {
        #pragma unroll
        for (int mi = 0; mi < 4; ++mi)
            #pragma unroll
            for (int j = 0; j < 4; ++j) {
                int gm = m0 + mh + mi * 16 + crow + j;
                if (gm < N_NODES) {
                    #pragma unroll
                    for (int ni = 0; ni < 4; ++ni) {
                        int n = nh + ni * 16 + ccol;
                        hall[((size_t)gm * 2 + c) * 128 + n] = acc[mi][ni][j];
                    }
                }
            }
    } else {
        float rbv[4];
        #pragma unroll
        for (int ni = 0; ni < 4; ++ni) rbv[ni] = root_b[nh + ni * 16 + ccol];
        #pragma unroll
        for (int mi = 0; mi < 4; ++mi)
            #pragma unroll
            for (int j = 0; j < 4; ++j) {
                int gm = m0 + mh + mi * 16 + crow + j;
                if (gm < N_NODES) {
                    #pragma unroll
                    for (int ni = 0; ni < 4; ++ni) {
                        int n = nh + ni * 16 + ccol;
                        out[(size_t)gm * 128 + n] = acc[mi][ni][j] + rbv[ni];
                    }
                }
            }
    }
}

// ---------------------------------------------------------------------------
// CSR build: histogram -> block scan -> block-sum scan -> add -> scatter ids
// ---------------------------------------------------------------------------
__global__ __launch_bounds__(256) void hist_kernel(
    const int* __restrict__ ei, int* __restrict__ deg)
{
    int i = blockIdx.x * 256 + threadIdx.x;
    if (i < N_EDGES) atomicAdd(&deg[ei[N_EDGES + i]], 1);
}

__global__ __launch_bounds__(256) void scan1_kernel(
    const int* __restrict__ deg, int* __restrict__ rp, int* __restrict__ bsum)
{
    __shared__ int s[256];
    int i = blockIdx.x * 256 + threadIdx.x;
    int v = (i < N_NODES) ? deg[i] : 0;
    s[threadIdx.x] = v;
    __syncthreads();
    #pragma unroll
    for (int off = 1; off < 256; off <<= 1) {
        int t = (threadIdx.x >= off) ? s[threadIdx.x - off] : 0;
        __syncthreads();
        s[threadIdx.x] += t;
        __syncthreads();
    }
    if (i < N_NODES) rp[i + 1] = s[threadIdx.x];
    if (threadIdx.x == 255) bsum[blockIdx.x] = s[255];
    if (i == 0) rp[0] = 0;
}

__global__ __launch_bounds__(256) void scan2_kernel(int* __restrict__ bsum, int nb)
{
    __shared__ int s[256];
    int tid = threadIdx.x;
    int v = (tid < nb) ? bsum[tid] : 0;
    s[tid] = v;
    __syncthreads();
    #pragma unroll
    for (int off = 1; off < 256; off <<= 1) {
        int t = (tid >= off) ? s[tid - off] : 0;
        __syncthreads();
        s[tid] += t;
        __syncthreads();
    }
    if (tid < nb) bsum[tid] = s[tid] - v;          // exclusive
}

__global__ __launch_bounds__(256) void scan3_kernel(
    int* __restrict__ rp, const int* __restrict__ bsum)
{
    int i = blockIdx.x * 256 + threadIdx.x;
    if (i < N_NODES) rp[i + 1] += bsum[blockIdx.x];
}

__global__ __launch_bounds__(256) void csr_scatter_kernel(
    const int* __restrict__ ei, const int* __restrict__ etype,
    const int* __restrict__ rp, int* __restrict__ cursor, int* __restrict__ skey)
{
    int i = blockIdx.x * 256 + threadIdx.x;
    if (i >= N_EDGES) return;
    int dst = ei[N_EDGES + i];
    int pos = rp[dst] + atomicAdd(&cursor[dst], 1);
    skey[pos] = (ei[i] << 1) | (etype[i] & 1);
}

// ---------------------------------------------------------------------------
// Fused per-node kernel: one wave per node, online softmax, 4-edge batches
// ---------------------------------------------------------------------------
__global__ __launch_bounds__(256) void node_agg_kernel(
    const int* __restrict__ rp, const int* __restrict__ skey,
    const float* __restrict__ hall, const float* __restrict__ att,
    float* __restrict__ out)
{
    const int lane = threadIdx.x & 63;
    const int node = (blockIdx.x * 256 + threadIdx.x) >> 6;
    if (node >= N_NODES) return;
    const int row0 = rp[node], row1 = rp[node + 1];
    if (row0 == row1) return;   // out keeps root contribution

    const float2 al0 = *(const float2*)&att[0 * 256 + lane * 2];
    const float2 ar0 = *(const float2*)&att[0 * 256 + 128 + lane * 2];
    const float2 al1 = *(const float2*)&att[1 * 256 + lane * 2];
    const float2 ar1 = *(const float2*)&att[1 * 256 + 128 + lane * 2];

    const float2 hd0 = *(const float2*)&hall[((size_t)node * 2 + 0) * 128 + lane * 2];
    const float2 hd1 = *(const float2*)&hall[((size_t)node * 2 + 1) * 128 + lane * 2];
    float dr0 = hd0.x * ar0.x + hd0.y * ar0.y;
    float dr1 = hd1.x * ar1.x + hd1.y * ar1.y;
    #pragma unroll
    for (int off = 32; off; off >>= 1) {
        dr0 += __shfl_xor(dr0, off);
        dr1 += __shfl_xor(dr1, off);
    }

    const float NINF = -__builtin_inff();
    float m = NINF, denom = 0.f, a0 = 0.f, a1 = 0.f;

    for (int j = row0; j < row1; j += 4) {
        const int je = row1 - 1;
        const int k0 = skey[j];
        const int k1 = skey[min(j + 1, je)];
        const int k2 = skey[min(j + 2, je)];
        const int k3 = skey[min(j + 3, je)];
        const int t0 = k0 & 1, t1 = k1 & 1, t2 = k2 & 1, t3 = k3 & 1;

        const float2 h0 = *(const float2*)&hall[((size_t)(k0 >> 1) * 2 + t0) * 128 + lane * 2];
        const float2 h1 = *(const float2*)&hall[((size_t)(k1 >> 1) * 2 + t1) * 128 + lane * 2];
        const float2 h2 = *(const float2*)&hall[((size_t)(k2 >> 1) * 2 + t2) * 128 + lane * 2];
        const float2 h3 = *(const float2*)&hall[((size_t)(k3 >> 1) * 2 + t3) * 128 + lane * 2];

        const float2 A0 = t0 ? al1 : al0;
        const float2 A1 = t1 ? al1 : al0;
        const float2 A2 = t2 ? al1 : al0;
        const float2 A3 = t3 ? al1 : al0;

        float p0 = h0.x * A0.x + h0.y * A0.y;
        float p1 = h1.x * A1.x + h1.y * A1.y;
        float p2 = h2.x * A2.x + h2.y * A2.y;
        float p3 = h3.x * A3.x + h3.y * A3.y;
        #pragma unroll
        for (int off = 32; off; off >>= 1) {
            p0 += __shfl_xor(p0, off);
            p1 += __shfl_xor(p1, off);
            p2 += __shfl_xor(p2, off);
            p3 += __shfl_xor(p3, off);
        }

        float e0 = p0 + (t0 ? dr1 : dr0);
        float e1 = p1 + (t1 ? dr1 : dr0);
        float e2 = p2 + (t2 ? dr1 : dr0);
        float e3 = p3 + (t3 ? dr1 : dr0);
        e0 = (e0 > 0.f) ? e0 : NEG_SLOPE * e0;
        e1 = (e1 > 0.f) ? e1 : NEG_SLOPE * e1;
        e2 = (e2 > 0.f) ? e2 : NEG_SLOPE * e2;
        e3 = (e3 > 0.f) ? e3 : NEG_SLOPE * e3;
        if (j + 1 > je) e1 = NINF;
        if (j + 2 > je) e2 = NINF;
        if (j + 3 > je) e3 = NINF;

        const float mx = fmaxf(fmaxf(fmaxf(e0, e1), fmaxf(e2, e3)), m);
        if (mx > m) {
            const float r = __expf(m - mx);
            denom *= r; a0 *= r; a1 *= r;
            m = mx;
        }
        const float w0 = __expf(e0 - m);
        const float w1 = __expf(e1 - m);
        const float w2 = __expf(e2 - m);
        const float w3 = __expf(e3 - m);
        denom += (w0 + w1) + (w2 + w3);
        a0 += w0 * h0.x + w1 * h1.x + w2 * h2.x + w3 * h3.x;
        a1 += w0 * h0.y + w1 * h1.y + w2 * h2.y + w3 * h3.y;
    }
    const float inv = 1.f / (denom + EPS_F);
    float* op = &out[(size_t)node * 128 + lane * 2];
    op[0] += a0 * inv;
    op[1] += a1 * inv;
}

// ---------------------------------------------------------------------------
extern "C" void kernel_launch(void* const* d_in, const int* in_sizes, int n_in,
                              void* d_out, int out_size, void* d_ws, size_t ws_size,
                              hipStream_t stream) {
    const float* x      = (const float*)d_in[0];
    const int*   ei     = (const int*)d_in[1];
    const int*   etype  = (const int*)d_in[2];
    const float* weight = (const float*)d_in[3];
    const float* att    = (const float*)d_in[4];
    const float* root_w = (const float*)d_in[5];
    const float* root_b = (const float*)d_in[6];
    float* out = (float*)d_out;

    // ws: hall [N*2*128] f32 | deg [N] | cursor [N] | rp [N+1] | bsum [256]
    //     | skey [E] | bt_hi [384*128] u16 | bt_lo [384*128] u16
    float* hall  = (float*)d_ws;
    int* deg     = (int*)(hall + (size_t)N_NODES * 2 * 128);
    int* cursor  = deg + N_NODES;
    int* rp      = cursor + N_NODES;
    int* bsum    = rp + (N_NODES + 1);
    int* skey    = bsum + 256;
    unsigned short* bt_hi = (unsigned short*)(skey + N_EDGES);
    unsigned short* bt_lo = bt_hi + 384 * 128;

    const int NB_E = (N_EDGES + 255) / 256;
    const int NB_N = (N_NODES + 255) / 256;

    hipMemsetAsync(deg, 0, sizeof(int) * (size_t)N_NODES * 2, stream);

    bprep_kernel<<<192, 256, 0, stream>>>(weight, root_w, bt_hi, bt_lo);

    mfma_gemm_kernel<<<3 * MBLK, 256, 0, stream>>>(
        x, bt_hi, bt_lo, root_b, hall, out);

    hist_kernel<<<NB_E, 256, 0, stream>>>(ei, deg);
    scan1_kernel<<<NB_N, 256, 0, stream>>>(deg, rp, bsum);
    scan2_kernel<<<1, 256, 0, stream>>>(bsum, NB_N);
    scan3_kernel<<<NB_N, 256, 0, stream>>>(rp, bsum);
    csr_scatter_kernel<<<NB_E, 256, 0, stream>>>(ei, etype, rp, cursor, skey);

    node_agg_kernel<<<(N_NODES + 3) / 4, 256, 0, stream>>>(
        rp, skey, hall, att, out);
}

// Round 11
// 240.763 us; speedup vs baseline: 1.4645x; 1.0374x over previous
//
#include <hip/hip_runtime.h>
#include <hip/hip_bf16.h>

#define N_NODES 50000
#define N_EDGES 500000
#define IN_CH 128
#define OUT_CH 128
#define N_TYPES 2
#define NEG_SLOPE 0.2f
#define EPS_F 1e-16f

typedef __attribute__((ext_vector_type(8))) short bf16x8;
typedef __attribute__((ext_vector_type(4))) float f32x4;

// fp32 -> bf16 (RNE) bit helpers
__device__ __forceinline__ unsigned short bf16_rne(float f) {
    unsigned int u = __float_as_uint(f);
    u += 0x7FFFu + ((u >> 16) & 1u);
    return (unsigned short)(u >> 16);
}
__device__ __forceinline__ float bf16_to_f32(unsigned short h) {
    return __uint_as_float(((unsigned int)h) << 16);
}

// ---------------------------------------------------------------------------
// Kernel 0: build Bt_hi/Bt_lo [384][128] bf16 (B transposed, split hi/lo)
//   rows 0..127  = W0^T, 128..255 = W1^T, 256..383 = root_w (already [o][k])
// ---------------------------------------------------------------------------
__global__ __launch_bounds__(256) void bprep_kernel(
    const float* __restrict__ weight, const float* __restrict__ root_w,
    unsigned short* __restrict__ bt_hi, unsigned short* __restrict__ bt_lo)
{
    int i = blockIdx.x * 256 + threadIdx.x;       // 0..49151
    if (i >= 384 * 128) return;
    int n = i >> 7, k = i & 127;
    float v;
    if (n < 256) {
        int t = n >> 7, o = n & 127;
        v = weight[(size_t)t * 16384 + (size_t)k * 128 + o];
    } else {
        v = root_w[(size_t)(n - 256) * 128 + k];
    }
    unsigned short h = bf16_rne(v);
    float lo = v - bf16_to_f32(h);
    bt_hi[i] = h;
    bt_lo[i] = bf16_rne(lo);
}

// ---------------------------------------------------------------------------
// Kernel 1: bf16x3 split-MFMA GEMM.  C[50048,384] = X[.,128] @ B[128,384]
//   A (x hi/lo) staged in 64KB LDS (swizzled) -> 2 blocks/CU;
//   B fragments loaded per-kstep straight from global (L2-hot, 64KB/chunk)
//   into registers. 4 waves * 64x64 out tile; 3 MFMA passes (hh,hl,lh).
// ---------------------------------------------------------------------------
#define MBLK 391
#define LSWZ(row, col) ((row) * 128 + ((col) ^ (((row) & 7) << 3)))

__global__ __launch_bounds__(256, 2) void mfma_gemm_kernel(
    const float* __restrict__ x,
    const unsigned short* __restrict__ bt_hi,
    const unsigned short* __restrict__ bt_lo,
    const float* __restrict__ root_b,
    float* __restrict__ hall, float* __restrict__ out)
{
    __shared__ unsigned short Ah[128 * 128];
    __shared__ unsigned short Al[128 * 128];

    const int tid = threadIdx.x;
    const int bid = blockIdx.x;
    const int c = bid / MBLK;            // output chunk 0..2
    const int m0 = (bid - c * MBLK) * 128;

    // --- stage A: x fp32 -> hi/lo bf16 (4096 float4 loads, 16/thread)
    {
        const float4* xg = (const float4*)x;
        #pragma unroll
        for (int it = 0; it < 16; ++it) {
            int idx = tid + it * 256;        // 0..4095
            int r = idx >> 5, c4 = idx & 31; // row, float4-in-row
            int gn = m0 + r;
            float4 v = make_float4(0.f, 0.f, 0.f, 0.f);
            if (gn < N_NODES) v = xg[(size_t)gn * 32 + c4];
            unsigned short h0 = bf16_rne(v.x), h1 = bf16_rne(v.y),
                           h2 = bf16_rne(v.z), h3 = bf16_rne(v.w);
            ushort4 hh = make_ushort4(h0, h1, h2, h3);
            ushort4 ll = make_ushort4(bf16_rne(v.x - bf16_to_f32(h0)),
                                      bf16_rne(v.y - bf16_to_f32(h1)),
                                      bf16_rne(v.z - bf16_to_f32(h2)),
                                      bf16_rne(v.w - bf16_to_f32(h3)));
            int off = LSWZ(r, c4 * 4);
            *(ushort4*)&Ah[off] = hh;
            *(ushort4*)&Al[off] = ll;
        }
    }
    __syncthreads();

    // --- compute: 4 waves, each 64x64 tile; B frags from global (L2)
    const int lane = tid & 63;
    const int w = tid >> 6;
    const int mh = (w >> 1) * 64;
    const int nh = (w & 1) * 64;
    const int lr = lane & 15;            // A row / B col within fragment
    const int lk = (lane >> 4) * 8;      // k offset within fragment

    // B fragment base: row (c*128 + nh + ni*16 + lr), col ks*32 + lk
    const unsigned short* bh_base =
        bt_hi + ((size_t)(c * 128 + nh + lr)) * 128 + lk;
    const unsigned short* bl_base =
        bt_lo + ((size_t)(c * 128 + nh + lr)) * 128 + lk;

    f32x4 acc[4][4];
    #pragma unroll
    for (int mi = 0; mi < 4; ++mi)
        #pragma unroll
        for (int ni = 0; ni < 4; ++ni)
            acc[mi][ni] = (f32x4){0.f, 0.f, 0.f, 0.f};

    #pragma unroll
    for (int ks = 0; ks < 4; ++ks) {
        const int ko = ks * 32 + lk;
        bf16x8 bh[4], bl[4];
        #pragma unroll
        for (int ni = 0; ni < 4; ++ni) {
            bh[ni] = *(const bf16x8*)(bh_base + ni * 2048 + ks * 32);
            bl[ni] = *(const bf16x8*)(bl_base + ni * 2048 + ks * 32);
        }
        bf16x8 ah[4], al[4];
        #pragma unroll
        for (int mi = 0; mi < 4; ++mi) {
            int off = LSWZ(mh + mi * 16 + lr, ko);
            ah[mi] = *(const bf16x8*)&Ah[off];
            al[mi] = *(const bf16x8*)&Al[off];
        }
        #pragma unroll
        for (int mi = 0; mi < 4; ++mi)
            #pragma unroll
            for (int ni = 0; ni < 4; ++ni) {
                acc[mi][ni] = __builtin_amdgcn_mfma_f32_16x16x32_bf16(
                    ah[mi], bh[ni], acc[mi][ni], 0, 0, 0);
                acc[mi][ni] = __builtin_amdgcn_mfma_f32_16x16x32_bf16(
                    ah[mi], bl[ni], acc[mi][ni], 0, 0, 0);
                acc[mi][ni] = __builtin_amdgcn_mfma_f32_16x16x32_bf16(
                    al[mi], bh[ni], acc[mi][ni], 0, 0, 0);
            }
    }

    // --- write C (verified layout: col = lane&15, row = (lane>>4)*4 + reg)
    const int crow = (lane >> 4) * 4;
    const int ccol = lane & 15;
    if (c < 2) {
        #pragma unroll
        for (int mi = 0; mi < 4; ++mi)
            #pragma unroll
            for (int j = 0; j < 4; ++j) {
                int gm = m0 + mh + mi * 16 + crow + j;
                if (gm < N_NODES) {
                    #pragma unroll
                    for (int ni = 0; ni < 4; ++ni) {
                        int n = nh + ni * 16 + ccol;
                        hall[((size_t)gm * 2 + c) * 128 + n] = acc[mi][ni][j];
                    }
                }
            }
    } else {
        float rbv[4];
        #pragma unroll
        for (int ni = 0; ni < 4; ++ni) rbv[ni] = root_b[nh + ni * 16 + ccol];
        #pragma unroll
        for (int mi = 0; mi < 4; ++mi)
            #pragma unroll
            for (int j = 0; j < 4; ++j) {
                int gm = m0 + mh + mi * 16 + crow + j;
                if (gm < N_NODES) {
                    #pragma unroll
                    for (int ni = 0; ni < 4; ++ni) {
                        int n = nh + ni * 16 + ccol;
                        out[(size_t)gm * 128 + n] = acc[mi][ni][j] + rbv[ni];
                    }
                }
            }
    }
}

// ---------------------------------------------------------------------------
// CSR build: histogram -> block scan -> block-sum scan -> add -> scatter ids
// ---------------------------------------------------------------------------
__global__ __launch_bounds__(256) void hist_kernel(
    const int* __restrict__ ei, int* __restrict__ deg)
{
    int i = blockIdx.x * 256 + threadIdx.x;
    if (i < N_EDGES) atomicAdd(&deg[ei[N_EDGES + i]], 1);
}

__global__ __launch_bounds__(256) void scan1_kernel(
    const int* __restrict__ deg, int* __restrict__ rp, int* __restrict__ bsum)
{
    __shared__ int s[256];
    int i = blockIdx.x * 256 + threadIdx.x;
    int v = (i < N_NODES) ? deg[i] : 0;
    s[threadIdx.x] = v;
    __syncthreads();
    #pragma unroll
    for (int off = 1; off < 256; off <<= 1) {
        int t = (threadIdx.x >= off) ? s[threadIdx.x - off] : 0;
        __syncthreads();
        s[threadIdx.x] += t;
        __syncthreads();
    }
    if (i < N_NODES) rp[i + 1] = s[threadIdx.x];
    if (threadIdx.x == 255) bsum[blockIdx.x] = s[255];
    if (i == 0) rp[0] = 0;
}

__global__ __launch_bounds__(256) void scan2_kernel(int* __restrict__ bsum, int nb)
{
    __shared__ int s[256];
    int tid = threadIdx.x;
    int v = (tid < nb) ? bsum[tid] : 0;
    s[tid] = v;
    __syncthreads();
    #pragma unroll
    for (int off = 1; off < 256; off <<= 1) {
        int t = (tid >= off) ? s[tid - off] : 0;
        __syncthreads();
        s[tid] += t;
        __syncthreads();
    }
    if (tid < nb) bsum[tid] = s[tid] - v;          // exclusive
}

__global__ __launch_bounds__(256) void scan3_kernel(
    int* __restrict__ rp, const int* __restrict__ bsum)
{
    int i = blockIdx.x * 256 + threadIdx.x;
    if (i < N_NODES) rp[i + 1] += bsum[blockIdx.x];
}

__global__ __launch_bounds__(256) void csr_scatter_kernel(
    const int* __restrict__ ei, const int* __restrict__ etype,
    const int* __restrict__ rp, int* __restrict__ cursor, int* __restrict__ skey)
{
    int i = blockIdx.x * 256 + threadIdx.x;
    if (i >= N_EDGES) return;
    int dst = ei[N_EDGES + i];
    int pos = rp[dst] + atomicAdd(&cursor[dst], 1);
    skey[pos] = (ei[i] << 1) | (etype[i] & 1);
}

// ---------------------------------------------------------------------------
// Fused per-node kernel v2: HALF-wave (32 lanes, float4 = 4 ch/lane) per
// node, 2 nodes per wave. Online softmax, branchless rescale, 4-edge batch
// per half (8 gathers in flight per wave). 5-step shuffle reduces.
// ---------------------------------------------------------------------------
__device__ __forceinline__ float dot4(float4 a, float4 b) {
    return a.x * b.x + a.y * b.y + a.z * b.z + a.w * b.w;
}

__global__ __launch_bounds__(256) void node_agg_kernel(
    const int* __restrict__ rp, const int* __restrict__ skey,
    const float* __restrict__ hall, const float* __restrict__ att,
    float* __restrict__ out)
{
    const int lane = threadIdx.x & 63;
    const int sl = lane & 31;            // sub-lane within half
    const int half = lane >> 5;
    const int wid = (blockIdx.x * 256 + threadIdx.x) >> 6;
    const int node = wid * 2 + half;
    if (node >= N_NODES) return;
    const int row0 = rp[node], row1 = rp[node + 1];

    const float4 al0 = *(const float4*)&att[0 * 256 + sl * 4];
    const float4 ar0 = *(const float4*)&att[0 * 256 + 128 + sl * 4];
    const float4 al1 = *(const float4*)&att[1 * 256 + sl * 4];
    const float4 ar1 = *(const float4*)&att[1 * 256 + 128 + sl * 4];

    // dst-side logit contribution, both types, reduced within the half
    const float4 hd0 = *(const float4*)&hall[((size_t)node * 2 + 0) * 128 + sl * 4];
    const float4 hd1 = *(const float4*)&hall[((size_t)node * 2 + 1) * 128 + sl * 4];
    float dr0 = dot4(hd0, ar0);
    float dr1 = dot4(hd1, ar1);
    #pragma unroll
    for (int off = 16; off; off >>= 1) {
        dr0 += __shfl_xor(dr0, off);
        dr1 += __shfl_xor(dr1, off);
    }

    const float NINF = -__builtin_inff();
    float m = NINF, denom = 0.f;
    float4 acc = make_float4(0.f, 0.f, 0.f, 0.f);

    for (int j = row0; j < row1; j += 4) {
        const int je = row1 - 1;
        const int k0 = skey[j];
        const int k1 = skey[min(j + 1, je)];
        const int k2 = skey[min(j + 2, je)];
        const int k3 = skey[min(j + 3, je)];
        const int t0 = k0 & 1, t1 = k1 & 1, t2 = k2 & 1, t3 = k3 & 1;

        const float4 h0 = *(const float4*)&hall[((size_t)(k0 >> 1) * 2 + t0) * 128 + sl * 4];
        const float4 h1 = *(const float4*)&hall[((size_t)(k1 >> 1) * 2 + t1) * 128 + sl * 4];
        const float4 h2 = *(const float4*)&hall[((size_t)(k2 >> 1) * 2 + t2) * 128 + sl * 4];
        const float4 h3 = *(const float4*)&hall[((size_t)(k3 >> 1) * 2 + t3) * 128 + sl * 4];

        float p0 = dot4(h0, t0 ? al1 : al0);
        float p1 = dot4(h1, t1 ? al1 : al0);
        float p2 = dot4(h2, t2 ? al1 : al0);
        float p3 = dot4(h3, t3 ? al1 : al0);
        #pragma unroll
        for (int off = 16; off; off >>= 1) {
            p0 += __shfl_xor(p0, off);
            p1 += __shfl_xor(p1, off);
            p2 += __shfl_xor(p2, off);
            p3 += __shfl_xor(p3, off);
        }

        float e0 = p0 + (t0 ? dr1 : dr0);
        float e1 = p1 + (t1 ? dr1 : dr0);
        float e2 = p2 + (t2 ? dr1 : dr0);
        float e3 = p3 + (t3 ? dr1 : dr0);
        e0 = (e0 > 0.f) ? e0 : NEG_SLOPE * e0;
        e1 = (e1 > 0.f) ? e1 : NEG_SLOPE * e1;
        e2 = (e2 > 0.f) ? e2 : NEG_SLOPE * e2;
        e3 = (e3 > 0.f) ? e3 : NEG_SLOPE * e3;
        // batch-tail mask: invalid -> -inf -> weight 0
        if (j + 1 > je) e1 = NINF;
        if (j + 2 > je) e2 = NINF;
        if (j + 3 > je) e3 = NINF;

        // branchless online rescale: r = exp(m_old - m_new); exp(0)=1
        const float mx = fmaxf(fmaxf(e0, e1), fmaxf(e2, e3));
        const float mn = fmaxf(m, mx);
        const float r = __expf(m - mn);     // first batch: exp(-inf) = 0
        m = mn;
        const float w0 = __expf(e0 - m);
        const float w1 = __expf(e1 - m);
        const float w2 = __expf(e2 - m);
        const float w3 = __expf(e3 - m);
        denom = denom * r + (w0 + w1) + (w2 + w3);
        acc.x = acc.x * r + w0 * h0.x + w1 * h1.x + w2 * h2.x + w3 * h3.x;
        acc.y = acc.y * r + w0 * h0.y + w1 * h1.y + w2 * h2.y + w3 * h3.y;
        acc.z = acc.z * r + w0 * h0.z + w1 * h1.z + w2 * h2.z + w3 * h3.z;
        acc.w = acc.w * r + w0 * h0.w + w1 * h1.w + w2 * h2.w + w3 * h3.w;
    }

    if (row0 < row1) {
        const float inv = 1.f / (denom + EPS_F);
        float4* op = (float4*)&out[(size_t)node * 128 + sl * 4];
        float4 o = *op;
        o.x += acc.x * inv;
        o.y += acc.y * inv;
        o.z += acc.z * inv;
        o.w += acc.w * inv;
        *op = o;
    }
}

// ---------------------------------------------------------------------------
extern "C" void kernel_launch(void* const* d_in, const int* in_sizes, int n_in,
                              void* d_out, int out_size, void* d_ws, size_t ws_size,
                              hipStream_t stream) {
    const float* x      = (const float*)d_in[0];
    const int*   ei     = (const int*)d_in[1];
    const int*   etype  = (const int*)d_in[2];
    const float* weight = (const float*)d_in[3];
    const float* att    = (const float*)d_in[4];
    const float* root_w = (const float*)d_in[5];
    const float* root_b = (const float*)d_in[6];
    float* out = (float*)d_out;

    // ws: hall [N*2*128] f32 | deg [N] | cursor [N] | rp [N+1] | bsum [256]
    //     | skey [E] | bt_hi [384*128] u16 | bt_lo [384*128] u16
    float* hall  = (float*)d_ws;
    int* deg     = (int*)(hall + (size_t)N_NODES * 2 * 128);
    int* cursor  = deg + N_NODES;
    int* rp      = cursor + N_NODES;
    int* bsum    = rp + (N_NODES + 1);
    int* skey    = bsum + 256;
    unsigned short* bt_hi = (unsigned short*)(skey + N_EDGES);
    unsigned short* bt_lo = bt_hi + 384 * 128;

    const int NB_E = (N_EDGES + 255) / 256;
    const int NB_N = (N_NODES + 255) / 256;

    hipMemsetAsync(deg, 0, sizeof(int) * (size_t)N_NODES * 2, stream);

    bprep_kernel<<<192, 256, 0, stream>>>(weight, root_w, bt_hi, bt_lo);

    mfma_gemm_kernel<<<3 * MBLK, 256, 0, stream>>>(
        x, bt_hi, bt_lo, root_b, hall, out);

    hist_kernel<<<NB_E, 256, 0, stream>>>(ei, deg);
    scan1_kernel<<<NB_N, 256, 0, stream>>>(deg, rp, bsum);
    scan2_kernel<<<1, 256, 0, stream>>>(bsum, NB_N);
    scan3_kernel<<<NB_N, 256, 0, stream>>>(rp, bsum);
    csr_scatter_kernel<<<NB_E, 256, 0, stream>>>(ei, etype, rp, cursor, skey);

    // 2 nodes per wave, 4 waves per block -> 8 nodes/block
    node_agg_kernel<<<(N_NODES + 7) / 8, 256, 0, stream>>>(
        rp, skey, hall, att, out);
}